// Round 1
// 731.038 us; speedup vs baseline: 1.1221x; 1.1221x over previous
//
#include <hip/hip_runtime.h>
#include <stdint.h>

#define L_DIM 2048
#define B_DIM 16
#define D_DIM 1024
#define M_DIM 32768              // L*B
#define K_DIM 1024               // D
#define N_DIM 3072               // 3D
#define SCALE_X 1.7320508075688772f

typedef __attribute__((ext_vector_type(8))) short short8;
typedef __attribute__((ext_vector_type(8))) unsigned short ushort8;
typedef __attribute__((ext_vector_type(4))) float f32x4;

__device__ __forceinline__ float bf2f(uint32_t b) {
    union { uint32_t u; float f; } v; v.u = b << 16; return v.f;
}
__device__ __forceinline__ uint16_t f2bf(float f) {
    union { float f; uint32_t u; } v; v.f = f;
    uint32_t u = v.u;
    return (uint16_t)((u + 0x7FFFu + ((u >> 16) & 1u)) >> 16);  // RNE
}

// async global->LDS, 16B per lane. LDS dest must be wave-uniform base + lane*16.
__device__ __forceinline__ void gload_lds16(const void* g, void* l) {
    __builtin_amdgcn_global_load_lds(
        (const __attribute__((address_space(1))) void*)g,
        (__attribute__((address_space(3))) void*)l,
        16 /*literal*/, 0, 0);
}

// ---- prep: weight (K x N fp32) -> Wt (N x K bf16), i.e. B^T ----
__global__ void prep_w_kernel(const float* __restrict__ w, uint16_t* __restrict__ wt) {
    int i = blockIdx.x * 256 + threadIdx.x;       // over K*N, coalesced read
    int k = i / N_DIM;
    int n = i - k * N_DIM;
    wt[n * K_DIM + k] = f2bf(w[i]);
}

// ---- prep: x (M x K fp32) -> xb (M x K bf16), coalesced both sides ----
__global__ void __launch_bounds__(256)
prep_x_kernel(const float* __restrict__ x, uint16_t* __restrict__ xb) {
    size_t i = (size_t)blockIdx.x * 256 + threadIdx.x;     // over M*K/8
    const float4 a = *(const float4*)(x + i * 8);
    const float4 b = *(const float4*)(x + i * 8 + 4);
    ushort8 o;
    o[0] = f2bf(a.x); o[1] = f2bf(a.y); o[2] = f2bf(a.z); o[3] = f2bf(a.w);
    o[4] = f2bf(b.x); o[5] = f2bf(b.y); o[6] = f2bf(b.z); o[7] = f2bf(b.w);
    *(ushort8*)(xb + i * 8) = o;
}

// ---- GEMM (fast path, m97 structure): both operands staged via global_load_lds ----
// 128x128 tile, BK=32, 4 waves each computing 4x4 frags of 16x16x32 bf16 MFMA.
__global__ void __launch_bounds__(256)
gemm_lds_kernel(const uint16_t* __restrict__ Ab,  // x bf16, M x K
                const uint16_t* __restrict__ Bt,  // Wt bf16, N x K
                uint16_t* __restrict__ u01,       // M x D x 2 (u0 low, u1 high) — aliases d_out h region
                uint16_t* __restrict__ u2p)       // M x D (ws)
{
    __shared__ uint16_t As[128 * 32];
    __shared__ uint16_t Bs[128 * 32];

    // supertile swizzle: groups of 8 m-tiles x all 24 n-tiles
    int bid = blockIdx.x;
    int mg = bid / 192;
    int tt = bid - mg * 192;
    int ntile = tt >> 3;
    int mtile = mg * 8 + (tt & 7);
    int m0 = mtile * 128;
    int n0 = ntile * 128;

    int t = threadIdx.x;
    int lane = t & 63;
    int w = t >> 6;
    int wm = (w >> 1) * 64;
    int wn = (w & 1) * 64;

    f32x4 acc[4][4] = {};

    int frow = lane & 15;
    int fk = (lane >> 4) * 8;

    // per-thread staging coords (chunk idx = c*256 + t; 16B per chunk)
    // row = idx>>2, ko = (idx&3)*8 ; LDS dest = idx*16 bytes = [row][ko] of [128][32]
    for (int kt = 0; kt < K_DIM; kt += 32) {
#pragma unroll
        for (int c = 0; c < 2; c++) {
            int idx = c * 256 + t;
            int row = idx >> 2;
            int ko = (idx & 3) * 8;
            gload_lds16(Ab + (size_t)(m0 + row) * K_DIM + kt + ko, As + idx * 8);
        }
#pragma unroll
        for (int c = 0; c < 2; c++) {
            int idx = c * 256 + t;
            int row = idx >> 2;
            int ko = (idx & 3) * 8;
            gload_lds16(Bt + (size_t)(n0 + row) * K_DIM + kt + ko, Bs + idx * 8);
        }
        __syncthreads();   // drains vmcnt -> LDS writes visible

        short8 af[4], bfr[4];
#pragma unroll
        for (int i = 0; i < 4; i++) {
            af[i]  = *(const short8*)(As + (wm + i * 16 + frow) * 32 + fk);
            bfr[i] = *(const short8*)(Bs + (wn + i * 16 + frow) * 32 + fk);
        }
#pragma unroll
        for (int i = 0; i < 4; i++)
#pragma unroll
            for (int j = 0; j < 4; j++)
                acc[i][j] = __builtin_amdgcn_mfma_f32_16x16x32_bf16(af[i], bfr[j], acc[i][j], 0, 0, 0);
        __syncthreads();   // all waves done reading before next overwrite
    }

    // epilogue: C/D layout col=lane&15, row=(lane>>4)*4+reg  [m89-verified]
    int colf = lane & 15;
    int rowq = (lane >> 4) * 4;
#pragma unroll
    for (int i = 0; i < 4; i++) {
#pragma unroll
        for (int j = 0; j < 4; j++) {
            int gcol = n0 + wn + j * 16 + colf;      // n = 3*d + comp
            int dq = gcol / 3;
            int cm = gcol - dq * 3;
#pragma unroll
            for (int r = 0; r < 4; r++) {
                int grow = m0 + wm + i * 16 + rowq + r;
                uint16_t v = f2bf(acc[i][j][r]);
                if (cm < 2) u01[(size_t)grow * 2048 + dq * 2 + cm] = v;
                else        u2p[(size_t)grow * 1024 + dq] = v;
            }
        }
    }
}

// ---- GEMM (fallback if workspace too small for xb): A fp32 converted in-register ----
__global__ void __launch_bounds__(256)
gemm_kernel(const float* __restrict__ A32,
            const uint16_t* __restrict__ Bt,
            uint16_t* __restrict__ u01,
            uint16_t* __restrict__ u2p)
{
    __shared__ uint16_t As[128 * 32];
    __shared__ uint16_t Bs[128 * 32];

    int bid = blockIdx.x;
    int mg = bid / 192;
    int tt = bid - mg * 192;
    int ntile = tt >> 3;
    int mtile = mg * 8 + (tt & 7);
    int m0 = mtile * 128;
    int n0 = ntile * 128;

    int t = threadIdx.x;
    int lane = t & 63;
    int w = t >> 6;
    int wm = (w >> 1) * 64;
    int wn = (w & 1) * 64;

    f32x4 acc[4][4] = {};

    int frow = lane & 15;
    int fk = (lane >> 4) * 8;

    for (int kt = 0; kt < K_DIM; kt += 32) {
#pragma unroll
        for (int c = 0; c < 4; c++) {
            int idx = c * 256 + t;
            int row = idx >> 3;
            int ko = (idx & 7) * 4;
            float4 v = *(const float4*)(A32 + (size_t)(m0 + row) * K_DIM + kt + ko);
            ushort4 o;
            o.x = f2bf(v.x); o.y = f2bf(v.y); o.z = f2bf(v.z); o.w = f2bf(v.w);
            *(ushort4*)(As + row * 32 + ko) = o;
        }
#pragma unroll
        for (int c = 0; c < 2; c++) {
            int idx = c * 256 + t;
            int row = idx >> 2;
            int ko = (idx & 3) * 8;
            short8 v = *(const short8*)(Bt + (size_t)(n0 + row) * K_DIM + kt + ko);
            *(short8*)(Bs + row * 32 + ko) = v;
        }
        __syncthreads();

        short8 af[4], bfr[4];
#pragma unroll
        for (int i = 0; i < 4; i++) {
            af[i]  = *(const short8*)(As + (wm + i * 16 + frow) * 32 + fk);
            bfr[i] = *(const short8*)(Bs + (wn + i * 16 + frow) * 32 + fk);
        }
#pragma unroll
        for (int i = 0; i < 4; i++)
#pragma unroll
            for (int j = 0; j < 4; j++)
                acc[i][j] = __builtin_amdgcn_mfma_f32_16x16x32_bf16(af[i], bfr[j], acc[i][j], 0, 0, 0);
        __syncthreads();
    }

    int colf = lane & 15;
    int rowq = (lane >> 4) * 4;
#pragma unroll
    for (int i = 0; i < 4; i++) {
#pragma unroll
        for (int j = 0; j < 4; j++) {
            int gcol = n0 + wn + j * 16 + colf;
            int dq = gcol / 3;
            int cm = gcol - dq * 3;
#pragma unroll
            for (int r = 0; r < 4; r++) {
                int grow = m0 + wm + i * 16 + rowq + r;
                uint16_t v = f2bf(acc[i][j][r]);
                if (cm < 2) u01[(size_t)grow * 2048 + dq * 2 + cm] = v;
                else        u2p[(size_t)grow * 1024 + dq] = v;
            }
        }
    }
}

// ---- scan: one thread per (b,d) chain, P-deep register prefetch ----
__global__ void __launch_bounds__(64)
scan_kernel(const uint32_t* u01,              // M x D of {u0,u1} (aliases out)
            const uint16_t* __restrict__ u2p, // M x D
            const float* __restrict__ x,      // fp32 x (L,B,D)
            const float* __restrict__ c0,
            const float* __restrict__ wc,
            const float* __restrict__ bias,
            float* out)                       // h (L,B,D) fp32 then c_final (B,D) fp32
{
    int cid = blockIdx.x * 64 + threadIdx.x;       // b*1024 + d
    int d = cid & (D_DIM - 1);
    float fw = wc[d], rw = wc[D_DIM + d];
    float fb = bias[d], rb = bias[D_DIM + d];
    float c = c0[cid];

    constexpr int P = 16;
    const int STEP = B_DIM * D_DIM;                // 16384
    uint32_t b01[P];
    uint16_t b2v[P];
    float bx[P];
#pragma unroll
    for (int j = 0; j < P; j++) {
        b01[j] = u01[cid + j * STEP];
        b2v[j] = u2p[cid + j * STEP];
        bx[j]  = x[cid + j * STEP];
    }

    for (int lb = 0; lb < L_DIM; lb += P) {
#pragma unroll
        for (int j = 0; j < P; j++) {
            int l = lb + j;
            uint32_t v01 = b01[j];
            float u2 = bf2f((uint32_t)b2v[j]);
            float xp = bx[j] * SCALE_X;

            int ln = l + P; if (ln > L_DIM - 1) ln = L_DIM - 1;
            int ri = cid + ln * STEP;
            b01[j] = u01[ri];
            b2v[j] = u2p[ri];
            bx[j]  = x[ri];

            float u0 = bf2f(v01 & 0xFFFFu);
            float u1 = bf2f(v01 >> 16);

            float ef = __expf(-(u1 + fb + c * fw));
            float er = __expf(-(u2 + rb + c * rw));
            float f = __builtin_amdgcn_rcpf(1.0f + ef);
            float r = __builtin_amdgcn_rcpf(1.0f + er);
            c = u0 + (c - u0) * f;
            float h = xp + (c - xp) * r;
            out[l * STEP + cid] = h;
        }
    }
    out[L_DIM * STEP + cid] = c;
}

extern "C" void kernel_launch(void* const* d_in, const int* in_sizes, int n_in,
                              void* d_out, int out_size, void* d_ws, size_t ws_size,
                              hipStream_t stream) {
    const float* x    = (const float*)d_in[0];
    const float* c0   = (const float*)d_in[1];
    const float* w    = (const float*)d_in[2];
    const float* wc   = (const float*)d_in[3];
    const float* bias = (const float*)d_in[4];

    // ws layout: wt 6 MB | u2 64 MB | xb 64 MB (fast path only)
    uint16_t* wt  = (uint16_t*)d_ws;
    uint16_t* u2p = (uint16_t*)((char*)d_ws + 6291456);
    const size_t XB_OFF = 6291456 + (size_t)M_DIM * D_DIM * 2;   // 70 MB
    const size_t WS_NEED = XB_OFF + (size_t)M_DIM * K_DIM * 2;   // 134 MB

    // u01 (M*D uint32) aliases the h region of d_out (same size & indexing).
    uint16_t* u01 = (uint16_t*)d_out;
    float* out = (float*)d_out;

    prep_w_kernel<<<(K_DIM * N_DIM) / 256, 256, 0, stream>>>(w, wt);

    if (ws_size >= WS_NEED) {
        uint16_t* xb = (uint16_t*)((char*)d_ws + XB_OFF);
        prep_x_kernel<<<(M_DIM * K_DIM / 8) / 256, 256, 0, stream>>>(x, xb);
        gemm_lds_kernel<<<(M_DIM / 128) * (N_DIM / 128), 256, 0, stream>>>(xb, wt, u01, u2p);
    } else {
        gemm_kernel<<<(M_DIM / 128) * (N_DIM / 128), 256, 0, stream>>>(x, wt, u01, u2p);
    }

    scan_kernel<<<(B_DIM * D_DIM) / 64, 64, 0, stream>>>((const uint32_t*)u01, u2p, x,
                                                         c0, wc, bias, out);
}

// Round 3
// 690.565 us; speedup vs baseline: 1.1878x; 1.0586x over previous
//
#include <hip/hip_runtime.h>
#include <stdint.h>

#define L_DIM 2048
#define B_DIM 16
#define D_DIM 1024
#define M_DIM 32768              // L*B
#define K_DIM 1024               // D
#define N_DIM 3072               // 3D
#define SCALE_X 1.7320508075688772f

typedef __attribute__((ext_vector_type(8))) short short8;
typedef __attribute__((ext_vector_type(8))) unsigned short ushort8;
typedef __attribute__((ext_vector_type(4))) float f32x4;

__device__ __forceinline__ float bf2f(uint32_t b) {
    union { uint32_t u; float f; } v; v.u = b << 16; return v.f;
}
__device__ __forceinline__ uint16_t f2bf(float f) {
    union { float f; uint32_t u; } v; v.f = f;
    uint32_t u = v.u;
    return (uint16_t)((u + 0x7FFFu + ((u >> 16) & 1u)) >> 16);  // RNE
}

// async global->LDS, 16B per lane. LDS dest is wave-uniform base + lane*16.
__device__ __forceinline__ void gl16(const uint16_t* g, uint16_t* l) {
    __builtin_amdgcn_global_load_lds(
        (const __attribute__((address_space(1))) void*)g,
        (__attribute__((address_space(3))) void*)l,
        16 /*literal*/, 0, 0);
}

// full fence: IR-level memory barrier + MIR scheduling barrier.
// raw s_barrier is IntrNoMem in LLVM -> memory ops CAN move across it
// unless we pin both levels (rule #18 / m152 race class).
__device__ __forceinline__ void fence_all() {
    asm volatile("" ::: "memory");
    __builtin_amdgcn_sched_barrier(0);
}
__device__ __forceinline__ void barrier_hard() {
    fence_all();
    __builtin_amdgcn_s_barrier();
    fence_all();
}

// ---- prep: weight (K x N fp32) -> Wt (N x K bf16), i.e. B^T ----
__global__ void prep_w_kernel(const float* __restrict__ w, uint16_t* __restrict__ wt) {
    int i = blockIdx.x * 256 + threadIdx.x;
    int k = i / N_DIM;
    int n = i - k * N_DIM;
    wt[n * K_DIM + k] = f2bf(w[i]);
}

// ---- prep: x (M x K fp32) -> xb (M x K bf16) ----
__global__ void __launch_bounds__(256)
prep_x_kernel(const float* __restrict__ x, uint16_t* __restrict__ xb) {
    size_t i = (size_t)blockIdx.x * 256 + threadIdx.x;
    const float4 a = *(const float4*)(x + i * 8);
    const float4 b = *(const float4*)(x + i * 8 + 4);
    ushort8 o;
    o[0] = f2bf(a.x); o[1] = f2bf(a.y); o[2] = f2bf(a.z); o[3] = f2bf(a.w);
    o[4] = f2bf(b.x); o[5] = f2bf(b.y); o[6] = f2bf(b.z); o[7] = f2bf(b.w);
    *(ushort8*)(xb + i * 8) = o;
}

// ================= 256x256 8-phase GEMM (T2+T3+T4+T5), hardened =================
// BM=BN=256, BK=64, 16 K-tiles, 8 waves (2M x 4N), per-wave out 128x64.
// LDS: 2 buffers x (A 256x64 + B 256x64) bf16 = 128 KiB.
// Swizzle: 16B slot index ^= (row&7) on global source + ds_read addr; LDS dest
// of global_load_lds stays linear (rule #21 both-sides-or-neither).
// Per K-tile T (staging T+1 into buf[nxt]):
//   barrier(recycle nxt) | STAGE h0 | vmcnt(2) | barrier(publish T)
//   | RD_B, RD_A(0) | QM00 | STAGE h1 | QM01 | RD_A(1) | STAGE h2 | QM11
//   | STAGE h3 | QM10
// vmcnt ledger: 8 outstanding at tile entry; +2 at STAGE h0 -> vmcnt(2)
// retires exactly the 8 loads of tile T. Never drains to 0 in the loop (T4).
__global__ void __launch_bounds__(512, 2)
gemm_8ph_kernel(const uint16_t* __restrict__ Ab,  // x bf16, M x K
                const uint16_t* __restrict__ Bt,  // Wt bf16, N x K
                uint16_t* __restrict__ u01,       // M x D x 2 (aliases d_out)
                uint16_t* __restrict__ u2p)       // M x D (ws)
{
    __shared__ uint16_t lds[65536];               // 128 KiB

    // supertile: groups of 8 m-tiles x all 12 n-tiles
    int bid = blockIdx.x;
    int mg = bid / 96;
    int tt = bid - mg * 96;
    int ntile = tt >> 3;
    int mtile = mg * 8 + (tt & 7);
    int m0 = mtile * 256;
    int n0 = ntile * 256;

    int t = threadIdx.x;
    int lane = t & 63;
    int w = t >> 6;
    int wm = (w >> 2) * 128;       // 2 m-groups
    int wn = (w & 3) * 64;         // 4 n-groups

    // staging coords: chunk idx within half = t; row = t>>3 (0..63), slot = t&7
    int row0 = t >> 3;
    int slot = t & 7;
    int swz_c = (slot ^ (row0 & 7)) * 8;   // inverse-swizzled global column (elems)
    const uint16_t* pA = Ab + (((size_t)(m0 + row0)) << 10) + swz_c;
    const uint16_t* pB = Bt + (((size_t)(n0 + row0)) << 10) + swz_c;

    int frow = lane & 15;
    int fkb = (lane >> 4) * 16;    // byte offset of 16B k-chunk within 128B row

    f32x4 acc[8][4] = {};
    short8 aF[4][2];               // one m-half at a time (reg reuse)
    short8 bF[4][2];               // all 4 n-frags of the wave

#define STAGE(hh, Tn) { \
    const uint16_t* gs = (((hh) < 2) ? pA : pB) + ((size_t)((hh) & 1) * 131072) + (size_t)(Tn) * 64; \
    uint16_t* ld = lds + nxtO + (hh) * 8192 + t * 8; \
    gl16(gs, ld); gl16(gs + 65536, ld + 4096); }

#define RD_A(mh) { \
    _Pragma("unroll") for (int mf = 0; mf < 4; mf++) \
    _Pragma("unroll") for (int ks = 0; ks < 2; ks++) { \
        int r = wm + (mh) * 64 + mf * 16 + frow; \
        int cb = (ks * 64 + fkb) ^ ((r & 7) << 4); \
        aF[mf][ks] = *(const short8*)(lds + curA + r * 64 + (cb >> 1)); } }

#define RD_B() { \
    _Pragma("unroll") for (int nf = 0; nf < 4; nf++) \
    _Pragma("unroll") for (int ks = 0; ks < 2; ks++) { \
        int r = wn + nf * 16 + frow; \
        int cb = (ks * 64 + fkb) ^ ((r & 7) << 4); \
        bF[nf][ks] = *(const short8*)(lds + curB + r * 64 + (cb >> 1)); } }

#define QM(mh, nh) { \
    __builtin_amdgcn_s_setprio(1); \
    _Pragma("unroll") for (int mf = 0; mf < 4; mf++) \
    _Pragma("unroll") for (int nj = 0; nj < 2; nj++) \
    _Pragma("unroll") for (int ks = 0; ks < 2; ks++) \
        acc[(mh) * 4 + mf][(nh) * 2 + nj] = __builtin_amdgcn_mfma_f32_16x16x32_bf16( \
            aF[mf][ks], bF[(nh) * 2 + nj][ks], acc[(mh) * 4 + mf][(nh) * 2 + nj], 0, 0, 0); \
    __builtin_amdgcn_s_setprio(0); }

    // prologue: stage tile 0 into buf0
    {
        int nxtO = 0;
        STAGE(0, 0); STAGE(1, 0); STAGE(2, 0); STAGE(3, 0);
    }

    for (int T = 0; T < 15; ++T) {
        int cur = T & 1;
        int curA = cur * 32768;
        int curB = curA + 16384;
        int nxtO = (cur ^ 1) * 32768;

        barrier_hard();                               // all reads of buf[nxt] done
        STAGE(0, T + 1);
        fence_all();
        asm volatile("s_waitcnt vmcnt(2)" ::: "memory");
        barrier_hard();                               // publish tile T
        RD_B();
        RD_A(0);
        QM(0, 0);
        fence_all();
        STAGE(1, T + 1);
        fence_all();
        QM(0, 1);
        RD_A(1);                                      // consumed at QM(1,*)
        fence_all();
        STAGE(2, T + 1);
        fence_all();
        QM(1, 1);
        fence_all();
        STAGE(3, T + 1);
        fence_all();
        QM(1, 0);
    }

    // ---- peeled tail: tile 15, no staging, full drain ----
    {
        int curA = 32768;   // 15&1 = 1
        int curB = curA + 16384;
        barrier_hard();
        asm volatile("s_waitcnt vmcnt(0)" ::: "memory");
        barrier_hard();
        RD_B();
        RD_A(0);
        QM(0, 0);
        QM(0, 1);
        RD_A(1);
        QM(1, 1);
        QM(1, 0);
    }

#undef STAGE
#undef RD_A
#undef RD_B
#undef QM

    // epilogue: C/D layout col=lane&15, row=(lane>>4)*4+reg  [m89-verified]
    int colf = lane & 15;
    int rowq = (lane >> 4) * 4;
#pragma unroll
    for (int i = 0; i < 8; i++) {
#pragma unroll
        for (int j = 0; j < 4; j++) {
            int gcol = n0 + wn + j * 16 + colf;      // n = 3*d + comp
            int dq = gcol / 3;
            int cm = gcol - dq * 3;
#pragma unroll
            for (int r = 0; r < 4; r++) {
                int grow = m0 + wm + i * 16 + rowq + r;
                uint16_t v = f2bf(acc[i][j][r]);
                if (cm < 2) u01[(size_t)grow * 2048 + dq * 2 + cm] = v;
                else        u2p[(size_t)grow * 1024 + dq] = v;
            }
        }
    }
}

// ---- fallback GEMM (ws too small for xb): 128^2, A fp32 in-register cvt ----
__global__ void __launch_bounds__(256)
gemm_kernel(const float* __restrict__ A32,
            const uint16_t* __restrict__ Bt,
            uint16_t* __restrict__ u01,
            uint16_t* __restrict__ u2p)
{
    __shared__ uint16_t As[128 * 32];
    __shared__ uint16_t Bs[128 * 32];

    int bid = blockIdx.x;
    int mg = bid / 192;
    int tt = bid - mg * 192;
    int ntile = tt >> 3;
    int mtile = mg * 8 + (tt & 7);
    int m0 = mtile * 128;
    int n0 = ntile * 128;

    int t = threadIdx.x;
    int lane = t & 63;
    int w = t >> 6;
    int wm = (w >> 1) * 64;
    int wn = (w & 1) * 64;

    f32x4 acc[4][4] = {};

    int frow = lane & 15;
    int fk = (lane >> 4) * 8;

    for (int kt = 0; kt < K_DIM; kt += 32) {
#pragma unroll
        for (int c = 0; c < 4; c++) {
            int idx = c * 256 + t;
            int row = idx >> 3;
            int ko = (idx & 7) * 4;
            float4 v = *(const float4*)(A32 + (size_t)(m0 + row) * K_DIM + kt + ko);
            ushort4 o;
            o.x = f2bf(v.x); o.y = f2bf(v.y); o.z = f2bf(v.z); o.w = f2bf(v.w);
            *(ushort4*)(As + row * 32 + ko) = o;
        }
#pragma unroll
        for (int c = 0; c < 2; c++) {
            int idx = c * 256 + t;
            int row = idx >> 2;
            int ko = (idx & 3) * 8;
            short8 v = *(const short8*)(Bt + (size_t)(n0 + row) * K_DIM + kt + ko);
            *(short8*)(Bs + row * 32 + ko) = v;
        }
        __syncthreads();

        short8 af[4], bfr[4];
#pragma unroll
        for (int i = 0; i < 4; i++) {
            af[i]  = *(const short8*)(As + (wm + i * 16 + frow) * 32 + fk);
            bfr[i] = *(const short8*)(Bs + (wn + i * 16 + frow) * 32 + fk);
        }
#pragma unroll
        for (int i = 0; i < 4; i++)
#pragma unroll
            for (int j = 0; j < 4; j++)
                acc[i][j] = __builtin_amdgcn_mfma_f32_16x16x32_bf16(af[i], bfr[j], acc[i][j], 0, 0, 0);
        __syncthreads();
    }

    int colf = lane & 15;
    int rowq = (lane >> 4) * 4;
#pragma unroll
    for (int i = 0; i < 4; i++) {
#pragma unroll
        for (int j = 0; j < 4; j++) {
            int gcol = n0 + wn + j * 16 + colf;
            int dq = gcol / 3;
            int cm = gcol - dq * 3;
#pragma unroll
            for (int r = 0; r < 4; r++) {
                int grow = m0 + wm + i * 16 + rowq + r;
                uint16_t v = f2bf(acc[i][j][r]);
                if (cm < 2) u01[(size_t)grow * 2048 + dq * 2 + cm] = v;
                else        u2p[(size_t)grow * 1024 + dq] = v;
            }
        }
    }
}

// ---- scan: one thread per (b,d) chain, P-deep register prefetch ----
__global__ void __launch_bounds__(64)
scan_kernel(const uint32_t* u01,              // M x D of {u0,u1} (aliases out)
            const uint16_t* __restrict__ u2p, // M x D
            const float* __restrict__ x,      // fp32 x (L,B,D)
            const float* __restrict__ c0,
            const float* __restrict__ wc,
            const float* __restrict__ bias,
            float* out)                       // h (L,B,D) fp32 then c_final (B,D)
{
    int cid = blockIdx.x * 64 + threadIdx.x;       // b*1024 + d
    int d = cid & (D_DIM - 1);
    float fw = wc[d], rw = wc[D_DIM + d];
    float fb = bias[d], rb = bias[D_DIM + d];
    float c = c0[cid];

    constexpr int P = 16;
    const int STEP = B_DIM * D_DIM;                // 16384
    uint32_t b01[P];
    uint16_t b2v[P];
    float bx[P];
#pragma unroll
    for (int j = 0; j < P; j++) {
        b01[j] = u01[cid + j * STEP];
        b2v[j] = u2p[cid + j * STEP];
        bx[j]  = x[cid + j * STEP];
    }

    for (int lb = 0; lb < L_DIM; lb += P) {
#pragma unroll
        for (int j = 0; j < P; j++) {
            int l = lb + j;
            uint32_t v01 = b01[j];
            float u2 = bf2f((uint32_t)b2v[j]);
            float xp = bx[j] * SCALE_X;

            int ln = l + P; if (ln > L_DIM - 1) ln = L_DIM - 1;
            int ri = cid + ln * STEP;
            b01[j] = u01[ri];
            b2v[j] = u2p[ri];
            bx[j]  = x[ri];

            float u0 = bf2f(v01 & 0xFFFFu);
            float u1 = bf2f(v01 >> 16);

            float ef = __expf(-(u1 + fb + c * fw));
            float er = __expf(-(u2 + rb + c * rw));
            float f = __builtin_amdgcn_rcpf(1.0f + ef);
            float r = __builtin_amdgcn_rcpf(1.0f + er);
            c = u0 + (c - u0) * f;
            float h = xp + (c - xp) * r;
            out[l * STEP + cid] = h;
        }
    }
    out[L_DIM * STEP + cid] = c;
}

extern "C" void kernel_launch(void* const* d_in, const int* in_sizes, int n_in,
                              void* d_out, int out_size, void* d_ws, size_t ws_size,
                              hipStream_t stream) {
    const float* x    = (const float*)d_in[0];
    const float* c0   = (const float*)d_in[1];
    const float* w    = (const float*)d_in[2];
    const float* wc   = (const float*)d_in[3];
    const float* bias = (const float*)d_in[4];

    // ws layout: wt 6 MB | u2 64 MB | xb 64 MB (fast path only)
    uint16_t* wt  = (uint16_t*)d_ws;
    uint16_t* u2p = (uint16_t*)((char*)d_ws + 6291456);
    const size_t XB_OFF = 6291456 + (size_t)M_DIM * D_DIM * 2;   // 70 MB
    const size_t WS_NEED = XB_OFF + (size_t)M_DIM * K_DIM * 2;   // 134 MB

    uint16_t* u01 = (uint16_t*)d_out;
    float* out = (float*)d_out;

    prep_w_kernel<<<(K_DIM * N_DIM) / 256, 256, 0, stream>>>(w, wt);

    if (ws_size >= WS_NEED) {
        uint16_t* xb = (uint16_t*)((char*)d_ws + XB_OFF);
        prep_x_kernel<<<(M_DIM * K_DIM / 8) / 256, 256, 0, stream>>>(x, xb);
        gemm_8ph_kernel<<<(M_DIM / 256) * (N_DIM / 256), 512, 0, stream>>>(xb, wt, u01, u2p);
    } else {
        gemm_kernel<<<(M_DIM / 128) * (N_DIM / 128), 256, 0, stream>>>(x, wt, u01, u2p);
    }

    scan_kernel<<<(B_DIM * D_DIM) / 64, 64, 0, stream>>>((const uint32_t*)u01, u2p, x,
                                                         c0, wc, bias, out);
}